// Round 10
// baseline (4041.591 us; speedup 1.0000x reference)
//
#include <hip/hip_runtime.h>
#include <math.h>

#define BB 8
#define LL 512
#define DD 256
#define NG4 1024
#define WGB 32     // WGs per batch
#define WR 16      // mem rows per WG
#define WU 8       // units per WG
#define MLD 264    // padded leading dim for mems tile

typedef __attribute__((ext_vector_type(4))) float f32x4;
typedef __attribute__((ext_vector_type(2))) unsigned u32x2;
typedef __attribute__((ext_vector_type(4))) unsigned u32x4;

// ---- workspace layout (float offsets) ----
static const size_t OFF_XW    = 0;
static const size_t OFF_F     = OFF_XW + (size_t)BB*LL*NG4;     // F = Wc_top @ Ww   (256x1024)
static const size_t OFF_BMW   = OFF_F + (size_t)DD*NG4;         // Bm = Wc_bot @ Ww  (256x1024)
static const size_t OFF_B2    = OFF_BMW + (size_t)DD*NG4;       // b2 = b_c@Ww + b_w (1024)
static const size_t OFF_HRT   = OFF_B2 + NG4;                   // [2][B][256] {val,tag}
static const size_t OFF_HWT   = OFF_HRT + (size_t)2*BB*DD*2;    // [2][B][256] {val,tag}
static const size_t OFF_RHOT  = OFF_HWT + (size_t)2*BB*DD*2;    // [B][32] pairs
static const size_t OFF_CHUNK = OFF_RHOT + (size_t)BB*WGB*2;    // [B][32] {pmax,psum,beta,tag}
static const size_t OFF_PMT   = OFF_CHUNK + (size_t)BB*WGB*4;   // [B][32][256] {val,tag}
static const size_t TOTAL_WS  = OFF_PMT + (size_t)BB*WGB*DD*2;  // floats

__device__ __forceinline__ float hsig(float x) {
    return fminf(fmaxf(0.2f*x + 0.5f, 0.0f), 1.0f);
}

// tagged 8B pair: {f32 value, u32 epoch} in ONE coherent instruction
__device__ __forceinline__ void st_pair(unsigned* p, float v, unsigned tag) {
    u32x2 d; d[0] = __float_as_uint(v); d[1] = tag;
    asm volatile("global_store_dwordx2 %0, %1, off sc0 sc1" :: "v"(p), "v"(d) : "memory");
}
__device__ __forceinline__ u32x2 ld_pair(const unsigned* p) {
    u32x2 r;
    asm volatile("global_load_dwordx2 %0, %1, off sc0 sc1\n\ts_waitcnt vmcnt(0)"
                 : "=&v"(r) : "v"(p) : "memory");
    return r;
}
__device__ __forceinline__ float poll_pair(const unsigned* p, unsigned tag) {
    for (;;) {
        u32x2 r = ld_pair(p);
        if (r[1] >= tag) return __uint_as_float(r[0]);
    }
}
__device__ __forceinline__ u32x4 ld_chunk(const unsigned* p) {
    u32x4 r;
    asm volatile("global_load_dwordx4 %0, %1, off sc0 sc1\n\ts_waitcnt vmcnt(0)"
                 : "=&v"(r) : "v"(p) : "memory");
    return r;
}

// 16 coherent dwordx4 loads (32 tagged pairs), single drain — one MALL round
__device__ __forceinline__ void ld_pmt16(
    const unsigned* q0, const unsigned* q1, const unsigned* q2, const unsigned* q3,
    const unsigned* q4, const unsigned* q5, const unsigned* q6, const unsigned* q7,
    u32x4& A0, u32x4& B0, u32x4& A1, u32x4& B1,
    u32x4& A2, u32x4& B2, u32x4& A3, u32x4& B3,
    u32x4& A4, u32x4& B4, u32x4& A5, u32x4& B5,
    u32x4& A6, u32x4& B6, u32x4& A7, u32x4& B7)
{
    asm volatile(
        "global_load_dwordx4 %0, %16, off sc0 sc1\n\t"
        "global_load_dwordx4 %1, %16, off offset:16 sc0 sc1\n\t"
        "global_load_dwordx4 %2, %17, off sc0 sc1\n\t"
        "global_load_dwordx4 %3, %17, off offset:16 sc0 sc1\n\t"
        "global_load_dwordx4 %4, %18, off sc0 sc1\n\t"
        "global_load_dwordx4 %5, %18, off offset:16 sc0 sc1\n\t"
        "global_load_dwordx4 %6, %19, off sc0 sc1\n\t"
        "global_load_dwordx4 %7, %19, off offset:16 sc0 sc1\n\t"
        "global_load_dwordx4 %8, %20, off sc0 sc1\n\t"
        "global_load_dwordx4 %9, %20, off offset:16 sc0 sc1\n\t"
        "global_load_dwordx4 %10, %21, off sc0 sc1\n\t"
        "global_load_dwordx4 %11, %21, off offset:16 sc0 sc1\n\t"
        "global_load_dwordx4 %12, %22, off sc0 sc1\n\t"
        "global_load_dwordx4 %13, %22, off offset:16 sc0 sc1\n\t"
        "global_load_dwordx4 %14, %23, off sc0 sc1\n\t"
        "global_load_dwordx4 %15, %23, off offset:16 sc0 sc1\n\t"
        "s_waitcnt vmcnt(0)"
        : "=&v"(A0), "=&v"(B0), "=&v"(A1), "=&v"(B1),
          "=&v"(A2), "=&v"(B2), "=&v"(A3), "=&v"(B3),
          "=&v"(A4), "=&v"(B4), "=&v"(A5), "=&v"(B5),
          "=&v"(A6), "=&v"(B6), "=&v"(A7), "=&v"(B7)
        : "v"(q0), "v"(q1), "v"(q2), "v"(q3),
          "v"(q4), "v"(q5), "v"(q6), "v"(q7)
        : "memory");
}

// ---- simple fp32 tiled GEMM ----
template<int TM, int TN, int TK>
__global__ void __launch_bounds__(256) gemm_nn(
    const float* __restrict__ A, int lda,
    const float* __restrict__ Bmat, int ldb,
    const float* __restrict__ bias,
    float* __restrict__ C, int ldc,
    int M, int N, int K)
{
    __shared__ float As[TK][TM];
    __shared__ float Bs[TK][TN];
    const int m0 = blockIdx.y * TM, n0 = blockIdx.x * TN;
    const int tid = threadIdx.x;
    const int tx = tid % (TN/4);
    const int ty = tid / (TN/4);
    float acc[4][4] = {};
    for (int k0 = 0; k0 < K; k0 += TK) {
        {
            const int e = tid*4;
            const int m = e / TK, k = e % TK;
            const float4 v = *reinterpret_cast<const float4*>(&A[(size_t)(m0+m)*lda + k0 + k]);
            As[k+0][m] = v.x; As[k+1][m] = v.y; As[k+2][m] = v.z; As[k+3][m] = v.w;
        }
        {
            const int e = tid*4;
            const int k = e / TN, n = e % TN;
            const float4 v = *reinterpret_cast<const float4*>(&Bmat[(size_t)(k0+k)*ldb + n0 + n]);
            Bs[k][n+0] = v.x; Bs[k][n+1] = v.y; Bs[k][n+2] = v.z; Bs[k][n+3] = v.w;
        }
        __syncthreads();
        #pragma unroll
        for (int kk = 0; kk < TK; ++kk) {
            float a[4], bv[4];
            #pragma unroll
            for (int i = 0; i < 4; ++i) a[i] = As[kk][ty*4+i];
            #pragma unroll
            for (int j = 0; j < 4; ++j) bv[j] = Bs[kk][tx*4+j];
            #pragma unroll
            for (int i = 0; i < 4; ++i)
                #pragma unroll
                for (int j = 0; j < 4; ++j) acc[i][j] += a[i]*bv[j];
        }
        __syncthreads();
    }
    #pragma unroll
    for (int i = 0; i < 4; ++i) {
        const int m = m0 + ty*4 + i;
        #pragma unroll
        for (int j = 0; j < 4; ++j) {
            const int n = n0 + tx*4 + j;
            C[(size_t)m*ldc + n] = acc[i][j] + (bias ? bias[n] : 0.0f);
        }
    }
}

// b2[n] = b_w[n] + sum_k b_c[k]*W_w[k][n]
__global__ void __launch_bounds__(256) b2_kernel(
    const float* __restrict__ bc, const float* __restrict__ Ww,
    const float* __restrict__ bw, float* __restrict__ B2)
{
    const int n = blockIdx.x*256 + threadIdx.x;
    float a = bw[n];
    for (int k = 0; k < DD; ++k) a += bc[k]*Ww[(size_t)k*NG4 + n];
    B2[n] = a;
}

// ---- fused reader+writer persistent kernel, fully tagged exchanges ----
// Per-step cross-WG chain: rho publish->poll (A1) and pm' publish->poll (A2->B1),
// each a single MALL event. hw poll (A3) and hr poll (B1) have >=1 phase slack.
// pm' excludes the hw term: m_rt = invS*(sum_w fw_w*pm'_w + gamma*hw),
// gamma = sum_w fw_w*beta_w (beta in chunk). WAR safety by causality:
// pm'(s+1) publication certifies A1(s+1) rho(s)-poll, which certifies peers'
// B1(s) consumption; HWT parity-double-buffered (certificate: pm'(s+1) after A3(s)).
__global__ void __launch_bounds__(256) fused_kernel(
    const float* __restrict__ XW, const float* __restrict__ Fw,
    const float* __restrict__ Bm, const float* __restrict__ B2,
    const float* __restrict__ Ur, const float* __restrict__ Uw,
    const float* __restrict__ x,
    unsigned* __restrict__ HRT, unsigned* __restrict__ HWT,
    unsigned* __restrict__ RHOT, unsigned* __restrict__ CHUNK,
    unsigned* __restrict__ PMT, float* __restrict__ out)
{
    extern __shared__ float sm[];
    float* Urs  = sm;              // [256][32]
    float* Uws  = Urs + 8192;      // [256][32]
    float* Fs   = Uws + 8192;      // [256][32]
    float* Bms  = Fs + 8192;       // [256][32]
    float* mems = Bms + 8192;      // [16][MLD]
    float* hr2  = mems + WR*MLD;   // [2][256] h_r parity slots
    float* hw   = hr2 + 512;       // 256
    float* ms   = hw + 256;        // 256
    float* zredR= ms + 256;        // 256
    float* zredW= zredR + 256;     // 256
    float* red4 = zredW + 256;     // [4][256]
    float* xws  = red4 + 1024;     // 32
    float* b2s  = xws + 32;        // 32
    float* zrs  = b2s + 32;        // 32
    float* zws  = zrs + 32;        // 32
    float* fwS  = zws + 32;        // 32
    float* d1   = fwS + 32;        // 16
    float* zp   = d1 + 16;         // 16
    float* esx  = zp + 16;         // 16
    float* wv   = esx + 16;        // 16
    float* cr   = wv + 16;         // 8
    float* cw   = cr + 8;          // 8
    float* misc = cw + 8;          // [0]=zp scale, [1]=invS, [3]=gamma

    const int b   = (int)blockIdx.x & 7;
    const int wg  = (int)blockIdx.x >> 3;   // 0..31
    const int tid = threadIdx.x;
    const int R0  = wg*WR;
    const int U0  = wg*WU;
    const int gc32 = (tid>>3)*DD + U0 + (tid&7);   // global col for lane<32

    // --- init: weight slices ---
    for (int it = 0; it < 32; ++it) {
        const int e = it*256 + tid;
        const int k = e >> 5, cl = e & 31;
        const int gc = (cl>>3)*DD + U0 + (cl&7);
        Urs[k*32+cl] = Ur[(size_t)k*NG4 + gc];
        Uws[k*32+cl] = Uw[(size_t)k*NG4 + gc];
        Fs [k*32+cl] = Fw[(size_t)k*NG4 + gc];
        Bms[k*32+cl] = Bm[(size_t)k*NG4 + gc];
    }
    if (tid < 32) b2s[tid] = B2[gc32];
    for (int r = 0; r < WR; ++r)
        mems[r*MLD + tid] = x[((size_t)b*LL + R0 + r)*DD + tid];
    // prologue: full h_r[0] computed locally (h=0 -> z = XW row 0)
    {
        const size_t base = (size_t)b*LL*NG4;
        const float zi = XW[base + tid];
        const float zg = XW[base + 512 + tid];
        const float zo = XW[base + 768 + tid];
        const float c0 = hsig(zi)*tanhf(zg);
        hr2[tid] = hsig(zo)*tanhf(c0);
        hr2[256 + tid] = 0.f;
        if (tid >= U0 && tid < U0+WU) cr[tid-U0] = c0;
    }
    if (tid < 16) { zp[tid] = 0.f; d1[tid] = 0.f; esx[tid] = 0.f; }
    if (tid < 8)  cw[tid] = 0.f;
    if (tid < 4)  misc[tid] = 0.f;
    __syncthreads();

    for (int s = 0; s <= LL; ++s) {
        const bool doW = (s >= 1);
        const unsigned us = (unsigned)s;
        float* hrN_s = hr2 + (s&1)*256;        // h_r[s]
        float* hrO_s = hr2 + ((s+1)&1)*256;    // h_r[s-1] = o_tau

        // ================= PHASE A =================
        // A1: rho poll -> d2 -> softmax -> chunk publish (no drain; wave 0 only)
        if (s <= LL-2 && tid < 32)
            xws[tid] = XW[((size_t)b*LL + s + 1)*NG4 + gc32];   // plain prefetch
        float rho_r = 0.f;
        if (s >= 2 && tid < 32) rho_r = poll_pair(RHOT + 2*(b*WGB + tid), us - 1u);
        if (tid < 32) {
            float d2 = rho_r;
            #pragma unroll
            for (int off = 16; off; off >>= 1) d2 += __shfl_xor(d2, off, 32);
            if (doW && tid < 16) {
                const float zpv = zp[tid];
                const float sc  = (1.f - zpv)*d1[tid] + zpv*d2;
                float m = sc;
                #pragma unroll
                for (int off = 8; off; off >>= 1) m = fmaxf(m, __shfl_xor(m, off, 16));
                const float e = __expf(sc - m);
                esx[tid] = e;
                wv[tid]  = e*(1.f - zpv);
                float sum = e, bp = e*zpv;
                #pragma unroll
                for (int off = 8; off; off >>= 1) {
                    sum += __shfl_xor(sum, off, 16);
                    bp  += __shfl_xor(bp,  off, 16);
                }
                if (tid == 0) {
                    u32x4 d; d[0] = __float_as_uint(m); d[1] = __float_as_uint(sum);
                    d[2] = __float_as_uint(bp); d[3] = us;
                    unsigned* cp = CHUNK + 4*(b*WGB + wg);
                    asm volatile("global_store_dwordx4 %0, %1, off sc0 sc1"
                                 :: "v"(cp), "v"(d) : "memory");
                }
            }
        }
        __syncthreads();   // SYNC_A1: wv visible

        // A2: publish tagged pm' (no hw term, no drain)
        if (doW) {
            float p = 0.f;
            #pragma unroll
            for (int r = 0; r < WR; ++r) p += wv[r]*mems[r*MLD + tid];
            st_pair(PMT + 2*(((size_t)b*WGB + wg)*DD + tid), p, us);
        }

        // A3: hw poll (parity slot; one full phase of slack)
        float hw_r = 0.f;
        if (s >= 2)
            hw_r = poll_pair(HWT + 2*((((size_t)((s-1)&1))*BB + b)*DD + tid), us - 1u);
        hw[tid] = hw_r;
        __syncthreads();   // SYNC_A2: hw visible
        if (s >= 2) {      // mem_{s-3} -> mem_{s-2} (own column)
            #pragma unroll
            for (int r = 0; r < WR; ++r) {
                const float z = zp[r];
                float* mp = &mems[r*MLD + tid];
                *mp = *mp*(1.f - z) + hw_r*z;
            }
        }
        if (doW) {         // hw@Uw + o@F GEMV partial
            const int kc = tid >> 5, cl = tid & 31, k0 = kc*32;
            float a = 0.f;
            #pragma unroll 8
            for (int k = k0; k < k0+32; ++k)
                a += hw[k]*Uws[k*32+cl] + hrO_s[k]*Fs[k*32+cl];
            zredW[tid] = a;
        }

        // ================= PHASE B =================
        // B1a: hr poll + chunk poll -> fw, invS, gamma
        float hrN_r = 0.f;
        if (s >= 1 && s <= LL-1)
            hrN_r = poll_pair(HRT + 2*((((size_t)(s&1))*BB + b)*DD + tid), us);
        if (doW && tid < 32) {
            const unsigned* cp = CHUNK + 4*(b*WGB + tid);
            u32x4 ck;
            do { ck = ld_chunk(cp); } while (ck[3] < us);
            const float pmx_r = __uint_as_float(ck[0]);
            const float ps_r  = __uint_as_float(ck[1]);
            const float bt_r  = __uint_as_float(ck[2]);
            float g = pmx_r;
            #pragma unroll
            for (int off = 16; off; off >>= 1) g = fmaxf(g, __shfl_xor(g, off, 32));
            const float fw = __expf(pmx_r - g);
            float S = ps_r*fw, gp = bt_r*fw;
            #pragma unroll
            for (int off = 16; off; off >>= 1) {
                S  += __shfl_xor(S,  off, 32);
                gp += __shfl_xor(gp, off, 32);
            }
            fwS[tid] = fw;
            if (tid == 0)  { misc[1] = 1.f/S; misc[3] = gp; }
            if (tid == wg) misc[0] = fw/S;
        }
        if (s >= 1 && s <= LL-1) hrN_s[tid] = hrN_r;
        __syncthreads();   // SYNC_B1: hrN, fwS, misc visible

        if (s <= LL-2) {   // reader GEMV partial
            const int kc = tid >> 5, cl = tid & 31, k0 = kc*32;
            float a = 0.f;
            #pragma unroll 8
            for (int k = k0; k < k0+32; ++k) a += hrN_s[k]*Urs[k*32+cl];
            zredR[tid] = a;
        }
        const int w0 = tid >> 6, dq = tid & 63;
        if (doW) {         // B1b: tagged pm' batch poll + weighted combine
            const unsigned* pmtb = PMT + 2*(size_t)b*WGB*DD;
            const unsigned* q0 = pmtb + 2*((w0+ 0)*DD + dq*4);
            const unsigned* q1 = pmtb + 2*((w0+ 4)*DD + dq*4);
            const unsigned* q2 = pmtb + 2*((w0+ 8)*DD + dq*4);
            const unsigned* q3 = pmtb + 2*((w0+12)*DD + dq*4);
            const unsigned* q4 = pmtb + 2*((w0+16)*DD + dq*4);
            const unsigned* q5 = pmtb + 2*((w0+20)*DD + dq*4);
            const unsigned* q6 = pmtb + 2*((w0+24)*DD + dq*4);
            const unsigned* q7 = pmtb + 2*((w0+28)*DD + dq*4);
            u32x4 A0,B0,A1,B1,A2,B2,A3,B3,A4,B4,A5,B5,A6,B6,A7,B7;
            for (;;) {
                ld_pmt16(q0,q1,q2,q3,q4,q5,q6,q7,
                         A0,B0,A1,B1,A2,B2,A3,B3,A4,B4,A5,B5,A6,B6,A7,B7);
                unsigned t0 = min(min(A0[1],A0[3]), min(B0[1],B0[3]));
                unsigned t1 = min(min(A1[1],A1[3]), min(B1[1],B1[3]));
                unsigned t2 = min(min(A2[1],A2[3]), min(B2[1],B2[3]));
                unsigned t3 = min(min(A3[1],A3[3]), min(B3[1],B3[3]));
                unsigned t4 = min(min(A4[1],A4[3]), min(B4[1],B4[3]));
                unsigned t5 = min(min(A5[1],A5[3]), min(B5[1],B5[3]));
                unsigned t6 = min(min(A6[1],A6[3]), min(B6[1],B6[3]));
                unsigned t7 = min(min(A7[1],A7[3]), min(B7[1],B7[3]));
                unsigned t = min(min(min(t0,t1),min(t2,t3)), min(min(t4,t5),min(t6,t7)));
                if (t >= us) break;
            }
            const float f0 = fwS[w0+ 0], f1 = fwS[w0+ 4], f2 = fwS[w0+ 8], f3 = fwS[w0+12];
            const float f4 = fwS[w0+16], f5 = fwS[w0+20], f6 = fwS[w0+24], f7 = fwS[w0+28];
            f32x4 acc;
            acc[0] = f0*__uint_as_float(A0[0]) + f1*__uint_as_float(A1[0])
                   + f2*__uint_as_float(A2[0]) + f3*__uint_as_float(A3[0])
                   + f4*__uint_as_float(A4[0]) + f5*__uint_as_float(A5[0])
                   + f6*__uint_as_float(A6[0]) + f7*__uint_as_float(A7[0]);
            acc[1] = f0*__uint_as_float(A0[2]) + f1*__uint_as_float(A1[2])
                   + f2*__uint_as_float(A2[2]) + f3*__uint_as_float(A3[2])
                   + f4*__uint_as_float(A4[2]) + f5*__uint_as_float(A5[2])
                   + f6*__uint_as_float(A6[2]) + f7*__uint_as_float(A7[2]);
            acc[2] = f0*__uint_as_float(B0[0]) + f1*__uint_as_float(B1[0])
                   + f2*__uint_as_float(B2[0]) + f3*__uint_as_float(B3[0])
                   + f4*__uint_as_float(B4[0]) + f5*__uint_as_float(B5[0])
                   + f6*__uint_as_float(B6[0]) + f7*__uint_as_float(B7[0]);
            acc[3] = f0*__uint_as_float(B0[2]) + f1*__uint_as_float(B1[2])
                   + f2*__uint_as_float(B2[2]) + f3*__uint_as_float(B3[2])
                   + f4*__uint_as_float(B4[2]) + f5*__uint_as_float(B5[2])
                   + f6*__uint_as_float(B6[2]) + f7*__uint_as_float(B7[2]);
            *(f32x4*)(red4 + w0*DD + dq*4) = acc;
        }
        __syncthreads();   // SYNC_B2: red4, zredR visible
        if (doW) {
            ms[tid] = (red4[tid] + red4[DD+tid] + red4[2*DD+tid] + red4[3*DD+tid]
                       + misc[3]*hw[tid]) * misc[1];
            if (tid < 16) zp[tid] = esx[tid]*misc[0];   // z_{s-1} for next step
        }
        __syncthreads();   // SYNC_B3: ms visible
        if (doW) {         // += ms@Bm  (zredW already holds hw@Uw + o@F)
            const int kc = tid >> 5, cl = tid & 31, k0 = kc*32;
            float a = zredW[tid];
            #pragma unroll 8
            for (int k = k0; k < k0+32; ++k) a += ms[k]*Bms[k*32+cl];
            zredW[tid] = a;
        }
        __syncthreads();   // SYNC_B4
        if (tid < 32) {
            if (doW) {
                float z = b2s[tid];
                #pragma unroll
                for (int q = 0; q < 8; ++q) z += zredW[q*32 + tid];
                zws[tid] = z;
            }
            if (s <= LL-2) {
                float z = xws[tid];
                #pragma unroll
                for (int q = 0; q < 8; ++q) z += zredR[q*32 + tid];
                zrs[tid] = z;
            }
        }
        __syncthreads();   // SYNC_B5: zws, zrs visible

        if (doW && tid < 8) {   // writer gates: publish tagged h_w (parity) + rho
            const float ig = hsig(zws[tid]);
            const float fg = hsig(zws[8+tid]);
            const float gg = tanhf(zws[16+tid]);
            const float og = hsig(zws[24+tid]);
            const float c  = fg*cw[tid] + ig*gg;
            cw[tid] = c;
            const float h = og*tanhf(c);
            st_pair(HWT + 2*((((size_t)(s&1))*BB + b)*DD + U0 + tid), h, us);
            if (s < LL) {
                float rr = h * hrN_s[U0 + tid];    // o_s . h_w(s-1), own slice
                rr += __shfl_down(rr, 4, 8);
                rr += __shfl_down(rr, 2, 8);
                rr += __shfl_down(rr, 1, 8);
                if (tid == 0) st_pair(RHOT + 2*(b*WGB + wg), rr, us);
            }
            if (s == LL) out[b*DD + U0 + tid] = h;
        }
        if (s <= LL-2 && tid < 8) {   // reader gates: publish tagged h_r[s+1]
            const float ig = hsig(zrs[tid]);
            const float fg = hsig(zrs[8+tid]);
            const float gg = tanhf(zrs[16+tid]);
            const float og = hsig(zrs[24+tid]);
            const float c  = fg*cr[tid] + ig*gg;
            cr[tid] = c;
            st_pair(HRT + 2*((((size_t)((s+1)&1))*BB + b)*DD + U0 + tid),
                    og*tanhf(c), us + 1u);
        }
        // d1' = h_r[s] . mem_{s-2} rows (WG-local, next step's scores)
        if (s < LL) {
            const int r = tid >> 4, j = tid & 15;
            float a = 0.f;
            const float* mrow = mems + r*MLD;
            #pragma unroll 4
            for (int d = j; d < DD; d += 16) a += hrN_s[d]*mrow[d];
            #pragma unroll
            for (int off = 8; off; off >>= 1) a += __shfl_down(a, off, 16);
            if (j == 0) d1[r] = a;
        }
        __syncthreads();   // SYNC_END: d1/wv/mems stable before next A1
    }
}

extern "C" void kernel_launch(void* const* d_in, const int* in_sizes, int n_in,
                              void* d_out, int out_size, void* d_ws, size_t ws_size,
                              hipStream_t stream) {
    const float* x   = (const float*)d_in[0];
    const float* W_r = (const float*)d_in[1];
    const float* U_r = (const float*)d_in[2];
    const float* b_r = (const float*)d_in[3];
    const float* W_w = (const float*)d_in[4];
    const float* U_w = (const float*)d_in[5];
    const float* b_w = (const float*)d_in[6];
    const float* W_c = (const float*)d_in[7];
    const float* b_c = (const float*)d_in[8];
    (void)in_sizes; (void)n_in;

    if (ws_size < TOTAL_WS * sizeof(float)) return;

    float* ws   = (float*)d_ws;
    float* XW   = ws + OFF_XW;
    float* Fmat = ws + OFF_F;
    float* Bmw  = ws + OFF_BMW;
    float* B2   = ws + OFF_B2;
    unsigned* HRT   = (unsigned*)(ws + OFF_HRT);
    unsigned* HWT   = (unsigned*)(ws + OFF_HWT);
    unsigned* RHOT  = (unsigned*)(ws + OFF_RHOT);
    unsigned* CHUNK = (unsigned*)(ws + OFF_CHUNK);
    unsigned* PMT   = (unsigned*)(ws + OFF_PMT);

    const int FUSED_LDS = 39800 * 4;   // 159200 B
    hipFuncSetAttribute((const void*)fused_kernel, hipFuncAttributeMaxDynamicSharedMemorySize, FUSED_LDS);

    // zero ALL tag-carrying buffers (HRT..PMT contiguous) — required every
    // launch: tags are monotonic per run and must restart below 1
    hipMemsetAsync(HRT, 0, (TOTAL_WS - OFF_HRT)*sizeof(float), stream);

    dim3 blk(256);
    // XW = x @ W_r + b_r        (4096 x 1024, K=256)
    gemm_nn<64,64,16><<<dim3(NG4/64, (BB*LL)/64), blk, 0, stream>>>(
        x, DD, W_r, NG4, b_r, XW, NG4, BB*LL, NG4, DD);
    // F  = W_c[:256,:] @ W_w    (256 x 1024, K=256)
    gemm_nn<64,64,16><<<dim3(NG4/64, DD/64), blk, 0, stream>>>(
        W_c, DD, W_w, NG4, nullptr, Fmat, NG4, DD, NG4, DD);
    // Bm = W_c[256:,:] @ W_w    (256 x 1024, K=256)
    gemm_nn<64,64,16><<<dim3(NG4/64, DD/64), blk, 0, stream>>>(
        W_c + (size_t)DD*DD, DD, W_w, NG4, nullptr, Bmw, NG4, DD, NG4, DD);
    // b2 = b_c @ W_w + b_w
    b2_kernel<<<dim3(NG4/256), blk, 0, stream>>>(b_c, W_w, b_w, B2);
    // fused persistent reader+writer (tagged-data sync, 2 RTT/step)
    fused_kernel<<<dim3(BB*WGB), blk, FUSED_LDS, stream>>>(
        XW, Fmat, Bmw, B2, U_r, U_w, x, HRT, HWT, RHOT, CHUNK, PMT, (float*)d_out);
}